// Round 6
// baseline (1594.744 us; speedup 1.0000x reference)
//
#include <hip/hip_runtime.h>

// Problem constants (B=4, N=2048, C=256, H=8, D=32, keep = int(2048*0.3) = 614)
#define BDIM 4
#define NSEQ 2048
#define CDIM 256
#define NHEADS 8
#define QB 4                     // query rows per block (1 per wave)
#define NT 32                    // K/V tiles of 64 rows
#define NKEEP 614                // int(2048 * (1.0 - 0.7))
#define ATTN_SCALE 0.17677669529663688f  // 32^-0.5

// -------------------------------------------------------------------------
// GEMM: C[M][Nt] = A[M][K] @ W[Nt][K]^T + bias[Nt]   (unchanged, validated)
// -------------------------------------------------------------------------
__global__ __launch_bounds__(256) void gemm_nt_bias(
    const float* __restrict__ A, const float* __restrict__ W,
    const float* __restrict__ bias, float* __restrict__ C,
    int M, int Nt, int K)
{
    __shared__ __align__(16) float As[32][68];
    __shared__ __align__(16) float Ws[32][68];
    const int tid = threadIdx.x;
    const int bm = blockIdx.x * 64;
    const int bn = blockIdx.y * 64;
    const int tm = tid >> 4;
    const int tn = tid & 15;
    const int lr = tid >> 2;
    const int lq = tid & 3;
    const float* Ap = A + (size_t)(bm + lr) * K + lq * 8;
    const float* Wp = W + (size_t)(bn + lr) * K + lq * 8;
    float acc[4][4] = {};

    for (int k0 = 0; k0 < K; k0 += 32) {
        float4 a0 = *(const float4*)(Ap + k0);
        float4 a1 = *(const float4*)(Ap + k0 + 4);
        float4 w0 = *(const float4*)(Wp + k0);
        float4 w1 = *(const float4*)(Wp + k0 + 4);
        __syncthreads();
        const int kq = lq * 8;
        As[kq+0][lr]=a0.x; As[kq+1][lr]=a0.y; As[kq+2][lr]=a0.z; As[kq+3][lr]=a0.w;
        As[kq+4][lr]=a1.x; As[kq+5][lr]=a1.y; As[kq+6][lr]=a1.z; As[kq+7][lr]=a1.w;
        Ws[kq+0][lr]=w0.x; Ws[kq+1][lr]=w0.y; Ws[kq+2][lr]=w0.z; Ws[kq+3][lr]=w0.w;
        Ws[kq+4][lr]=w1.x; Ws[kq+5][lr]=w1.y; Ws[kq+6][lr]=w1.z; Ws[kq+7][lr]=w1.w;
        __syncthreads();
        #pragma unroll
        for (int k = 0; k < 32; ++k) {
            float4 av = *(const float4*)&As[k][tm*4];
            float4 wv = *(const float4*)&Ws[k][tn*4];
            acc[0][0] += av.x*wv.x; acc[0][1] += av.x*wv.y; acc[0][2] += av.x*wv.z; acc[0][3] += av.x*wv.w;
            acc[1][0] += av.y*wv.x; acc[1][1] += av.y*wv.y; acc[1][2] += av.y*wv.z; acc[1][3] += av.y*wv.w;
            acc[2][0] += av.z*wv.x; acc[2][1] += av.z*wv.y; acc[2][2] += av.z*wv.z; acc[2][3] += av.z*wv.w;
            acc[3][0] += av.w*wv.x; acc[3][1] += av.w*wv.y; acc[3][2] += av.w*wv.z; acc[3][3] += av.w*wv.w;
        }
    }
    float4 bb = *(const float4*)(bias + bn + tn*4);
    #pragma unroll
    for (int i = 0; i < 4; ++i) {
        float4 o;
        o.x = acc[i][0] + bb.x;
        o.y = acc[i][1] + bb.y;
        o.z = acc[i][2] + bb.z;
        o.w = acc[i][3] + bb.w;
        *(float4*)(C + (size_t)(bm + tm*4 + i) * Nt + bn + tn*4) = o;
    }
}

// -------------------------------------------------------------------------
// Fused sparse attention. QB=4 rows/block, 1 row per wave. Scores in LDS.
// Ring-3 of 64-row tiles, counted vmcnt(2): wait(tile t) -> barrier ->
// stage(t+2) -> compute(t). 4-lane dim-partials reduced via DPP quad-perm
// (pure VALU, no DS). Radix pass 3 (top byte) is histogrammed inline in
// phase B; phase C does the remaining 3 passes with float4 reads.
// -------------------------------------------------------------------------
__device__ __forceinline__ unsigned int f2key(float f) {
    unsigned int u = __float_as_uint(f);
    return (u & 0x80000000u) ? ~u : (u | 0x80000000u);  // monotone order-preserving
}

// cross-lane add within quad: xor1 = quad_perm(1,0,3,2)=0xB1, xor2 = (2,3,0,1)=0x4E
__device__ __forceinline__ float dpp_xor1_add(float x) {
    int s = __builtin_amdgcn_mov_dpp(__float_as_int(x), 0xB1, 0xF, 0xF, true);
    return x + __int_as_float(s);
}
__device__ __forceinline__ float dpp_xor2_add(float x) {
    int s = __builtin_amdgcn_mov_dpp(__float_as_int(x), 0x4E, 0xF, 0xF, true);
    return x + __int_as_float(s);
}

typedef __attribute__((address_space(1))) const void gas_void;
typedef __attribute__((address_space(3))) void las_void;

__device__ __forceinline__ void gload_lds16(const float* g, float4* l) {
    __builtin_amdgcn_global_load_lds((gas_void*)g, (las_void*)l, 16, 0, 0);
}

// stage 64 rows x 32 floats (global row stride 768) into dst4[512].
// LDS slot u holds global chunk ((u&7) ^ (row&7)): XOR swizzle via source.
__device__ __forceinline__ void stage64(const float* __restrict__ g, float4* dst4, int tid) {
    const int s0 = tid, s1 = tid + 256;
    const int r0 = s0 >> 3, c0 = (s0 & 7) ^ (r0 & 7);
    const int r1 = s1 >> 3, c1 = (s1 & 7) ^ (r1 & 7);
    gload_lds16(g + (size_t)r0 * 768 + c0 * 4, dst4 + s0);
    gload_lds16(g + (size_t)r1 * 768 + c1 * 4, dst4 + s1);
}

// raw barrier: drain LDS ops, do NOT drain vmcnt (keeps prefetch in flight)
#define RBAR() do { asm volatile("s_waitcnt lgkmcnt(0)" ::: "memory"); \
                    __builtin_amdgcn_s_barrier();                      \
                    asm volatile("" ::: "memory"); } while (0)
#define LGKM0() asm volatile("s_waitcnt lgkmcnt(0)" ::: "memory")
// counted waits: tile t landed while t+1 (2 loads/wave) stays in flight
#define VMW(t, last) do { if ((t) < (last)) asm volatile("s_waitcnt vmcnt(2)" ::: "memory"); \
                          else              asm volatile("s_waitcnt vmcnt(0)" ::: "memory"); } while (0)

__global__ __launch_bounds__(256, 2) void sparse_attn(
    const float* __restrict__ qkv, float* __restrict__ aout)
{
    __shared__ __align__(16) float4 kbuf[3][512];     // 24 KB ring (K then V)
    __shared__ __align__(16) float  sbuf[QB * NSEQ];  // 32 KB scores / p-values
    __shared__ __align__(16) unsigned int hist[QB * 256]; // 4 KB
    __shared__ unsigned int prefS[QB];
    __shared__ int   remS[QB];
    __shared__ float zS[QB];

    const int tid = threadIdx.x;
    const int w   = tid >> 6;       // wave id = row id (0..3)
    const int l   = tid & 63;
    const int p   = l & 3;          // dim-chunk pair (8 floats at 8p)
    const int jg  = l >> 2;         // 0..15
    const int jloc = w * 16 + jg;   // this thread's column within a 64-tile
    const int sw1 = (2 * p)     ^ (jloc & 7);
    const int sw2 = (2 * p + 1) ^ (jloc & 7);

    const int blk = blockIdx.x;
    const int nqb = NSEQ / QB;      // 512
    const int bh  = blk / nqb;
    const int qblk = blk % nqb;
    const int b = bh / NHEADS, h = bh % NHEADS;
    const int n0 = qblk * QB;

    const float* base = qkv + (size_t)b * NSEQ * 768;
    const float* gk = base + 256 + h * 32;
    const float* gv = base + 512 + h * 32;

    // ---- Q rows 0..3, this lane's 8-dim chunk, pre-scaled, in registers ----
    float4 qa[QB], qc[QB];
    {
        const float* gq = base + (size_t)n0 * 768 + h * 32 + p * 8;
        #pragma unroll
        for (int r = 0; r < QB; ++r) {
            float4 x0 = *(const float4*)(gq + (size_t)r * 768);
            float4 x1 = *(const float4*)(gq + (size_t)r * 768 + 4);
            qa[r].x = x0.x * ATTN_SCALE; qa[r].y = x0.y * ATTN_SCALE;
            qa[r].z = x0.z * ATTN_SCALE; qa[r].w = x0.w * ATTN_SCALE;
            qc[r].x = x1.x * ATTN_SCALE; qc[r].y = x1.y * ATTN_SCALE;
            qc[r].z = x1.z * ATTN_SCALE; qc[r].w = x1.w * ATTN_SCALE;
        }
    }
    // zero the pass-3 histogram (filled inline during phase B)
    {
        uint4 z4; z4.x = 0u; z4.y = 0u; z4.z = 0u; z4.w = 0u;
        *(uint4*)(hist + tid * 4) = z4;
    }
    if (tid < QB) { prefS[tid] = 0u; remS[tid] = NKEEP; }

    // ---- Phase B: scores + top-byte histogram. Ring-3, counted vmcnt. ----
    stage64(gk, &kbuf[0][0], tid);
    stage64(gk + (size_t)64 * 768, &kbuf[1][0], tid);
    #pragma unroll 1
    for (int t = 0; t < NT; ++t) {
        VMW(t, NT - 1);  // tile t landed; t+1 may stay in flight
        RBAR();          // all waves landed + done reading tile t-1
        if (t + 2 < NT) stage64(gk + (size_t)(t + 2) * 64 * 768, &kbuf[(t + 2) % 3][0], tid);
        const float4* kb = &kbuf[t % 3][0];
        float4 k0 = kb[jloc * 8 + sw1];
        float4 k1 = kb[jloc * 8 + sw2];
        float sc0 = qa[0].x*k0.x + qa[0].y*k0.y + qa[0].z*k0.z + qa[0].w*k0.w
                  + qc[0].x*k1.x + qc[0].y*k1.y + qc[0].z*k1.z + qc[0].w*k1.w;
        float sc1 = qa[1].x*k0.x + qa[1].y*k0.y + qa[1].z*k0.z + qa[1].w*k0.w
                  + qc[1].x*k1.x + qc[1].y*k1.y + qc[1].z*k1.z + qc[1].w*k1.w;
        float sc2 = qa[2].x*k0.x + qa[2].y*k0.y + qa[2].z*k0.z + qa[2].w*k0.w
                  + qc[2].x*k1.x + qc[2].y*k1.y + qc[2].z*k1.z + qc[2].w*k1.w;
        float sc3 = qa[3].x*k0.x + qa[3].y*k0.y + qa[3].z*k0.z + qa[3].w*k0.w
                  + qc[3].x*k1.x + qc[3].y*k1.y + qc[3].z*k1.z + qc[3].w*k1.w;
        // reduce 4 dim-chunks within each quad: pure-VALU DPP butterfly
        sc0 = dpp_xor2_add(dpp_xor1_add(sc0));
        sc1 = dpp_xor2_add(dpp_xor1_add(sc1));
        sc2 = dpp_xor2_add(dpp_xor1_add(sc2));
        sc3 = dpp_xor2_add(dpp_xor1_add(sc3));
        float myv = (p == 0) ? sc0 : (p == 1) ? sc1 : (p == 2) ? sc2 : sc3;
        sbuf[p * NSEQ + t * 64 + jloc] = myv;
        atomicAdd(&hist[p * 256 + (f2key(myv) >> 24)], 1u);  // radix pass 3 inline
    }
    RBAR();   // scores + all waves' histogram atomics visible
    // V tiles 0,1 fly across the whole select/softmax phase
    // slots continue the modular sequence: (NT)%3=2, (NT+1)%3=0 (safe: held K tiles 29,30)
    stage64(gv, &kbuf[2][0], tid);
    stage64(gv + (size_t)64 * 768, &kbuf[0][0], tid);

    // ---- Phase C: exact 614th-largest per row. Wave w owns row w only. ----
    unsigned int* hrow = hist + w * 256;
    #pragma unroll 1
    for (int pass = 3; pass >= 0; --pass) {
        const int sh = pass * 8;
        const unsigned int pr = prefS[w];
        const int remv = remS[w];
        if (pass != 3) {
            const unsigned int hmsk = 0xFFFFFFFFu << (sh + 8);
            uint4 z4; z4.x = 0u; z4.y = 0u; z4.z = 0u; z4.w = 0u;
            *(uint4*)(hrow + l * 4) = z4;
            LGKM0();
            #pragma unroll 2
            for (int e = 0; e < 8; ++e) {
                float4 v = *(const float4*)&sbuf[w * NSEQ + l * 4 + 256 * e];
                unsigned int k0 = f2key(v.x), k1 = f2key(v.y), k2 = f2key(v.z), k3 = f2key(v.w);
                if ((k0 & hmsk) == pr) atomicAdd(&hrow[(k0 >> sh) & 255u], 1u);
                if ((k1 & hmsk) == pr) atomicAdd(&hrow[(k1 >> sh) & 255u], 1u);
                if ((k2 & hmsk) == pr) atomicAdd(&hrow[(k2 >> sh) & 255u], 1u);
                if ((k3 & hmsk) == pr) atomicAdd(&hrow[(k3 >> sh) & 255u], 1u);
            }
            LGKM0();
        }
        uint4 c4 = *(const uint4*)(hrow + l * 4);
        unsigned int cnt[4] = { c4.x, c4.y, c4.z, c4.w };
        unsigned int part = cnt[0] + cnt[1] + cnt[2] + cnt[3];
        unsigned int suf = part;
        #pragma unroll
        for (int dlt = 1; dlt < 64; dlt <<= 1) {
            unsigned int v = __shfl_down(suf, dlt);
            if (l + dlt < 64) suf += v;
        }
        unsigned int run = suf - part;   // elems in bins owned by lanes > l
        #pragma unroll
        for (int i = 3; i >= 0; --i) {
            if ((int)run < remv && remv <= (int)(run + cnt[i])) {
                remS[w]  = remv - (int)run;
                prefS[w] = pr | ((unsigned int)(l * 4 + i) << sh);
            }
            run += cnt[i];
        }
        LGKM0();  // pref/rem visible wave-wide before next pass
    }

    // ---- Phase D: masked softmax on row w (float4, in LDS) ----
    {
        unsigned int key = prefS[w];
        unsigned int u = (key & 0x80000000u) ? (key & 0x7FFFFFFFu) : ~key;
        const float thr = __uint_as_float(u);
        float mx = 0.f;   // >=1434 masked zeros always present
        #pragma unroll 2
        for (int e = 0; e < 8; ++e) {
            float* sp = &sbuf[w * NSEQ + l * 4 + 256 * e];
            float4 v = *(const float4*)sp;
            v.x = (v.x >= thr) ? v.x : 0.f;
            v.y = (v.y >= thr) ? v.y : 0.f;
            v.z = (v.z >= thr) ? v.z : 0.f;
            v.w = (v.w >= thr) ? v.w : 0.f;
            *(float4*)sp = v;
            mx = fmaxf(mx, fmaxf(fmaxf(v.x, v.y), fmaxf(v.z, v.w)));
        }
        #pragma unroll
        for (int d2 = 32; d2 >= 1; d2 >>= 1) mx = fmaxf(mx, __shfl_xor(mx, d2));
        float Z = 0.f;
        #pragma unroll 2
        for (int e = 0; e < 8; ++e) {
            float* sp = &sbuf[w * NSEQ + l * 4 + 256 * e];
            float4 v = *(const float4*)sp;
            v.x = __expf(v.x - mx); v.y = __expf(v.y - mx);
            v.z = __expf(v.z - mx); v.w = __expf(v.w - mx);
            *(float4*)sp = v;
            Z += v.x + v.y + v.z + v.w;
        }
        #pragma unroll
        for (int d2 = 32; d2 >= 1; d2 >>= 1) Z += __shfl_xor(Z, d2);
        if (l == 0) zS[w] = Z;
    }

    // ---- Phase E: PV streaming over V, same ring discipline ----
    float4 oa0, oa1, oa2, oa3, ob0, ob1, ob2, ob3;
    oa0.x=0;oa0.y=0;oa0.z=0;oa0.w=0; ob0=oa0; oa1=oa0; ob1=oa0;
    oa2=oa0; ob2=oa0; oa3=oa0; ob3=oa0;
    #pragma unroll 1
    for (int t = 0; t < NT; ++t) {
        VMW(t, NT - 1);
        RBAR();   // iter 0: also publishes p-values (sbuf) and zS to all waves
        if (t + 2 < NT) stage64(gv + (size_t)(t + 2) * 64 * 768, &kbuf[(NT + t + 2) % 3][0], tid);
        const float4* vb = &kbuf[(NT + t) % 3][0];
        float4 v0 = vb[jloc * 8 + sw1];
        float4 v1 = vb[jloc * 8 + sw2];
        const int j = t * 64 + jloc;
        float p0 = sbuf[0 * NSEQ + j];
        float p1 = sbuf[1 * NSEQ + j];
        float p2 = sbuf[2 * NSEQ + j];
        float p3 = sbuf[3 * NSEQ + j];
        oa0.x=fmaf(p0,v0.x,oa0.x); oa0.y=fmaf(p0,v0.y,oa0.y); oa0.z=fmaf(p0,v0.z,oa0.z); oa0.w=fmaf(p0,v0.w,oa0.w);
        ob0.x=fmaf(p0,v1.x,ob0.x); ob0.y=fmaf(p0,v1.y,ob0.y); ob0.z=fmaf(p0,v1.z,ob0.z); ob0.w=fmaf(p0,v1.w,ob0.w);
        oa1.x=fmaf(p1,v0.x,oa1.x); oa1.y=fmaf(p1,v0.y,oa1.y); oa1.z=fmaf(p1,v0.z,oa1.z); oa1.w=fmaf(p1,v0.w,oa1.w);
        ob1.x=fmaf(p1,v1.x,ob1.x); ob1.y=fmaf(p1,v1.y,ob1.y); ob1.z=fmaf(p1,v1.z,ob1.z); ob1.w=fmaf(p1,v1.w,ob1.w);
        oa2.x=fmaf(p2,v0.x,oa2.x); oa2.y=fmaf(p2,v0.y,oa2.y); oa2.z=fmaf(p2,v0.z,oa2.z); oa2.w=fmaf(p2,v0.w,oa2.w);
        ob2.x=fmaf(p2,v1.x,ob2.x); ob2.y=fmaf(p2,v1.y,ob2.y); ob2.z=fmaf(p2,v1.z,ob2.z); ob2.w=fmaf(p2,v1.w,ob2.w);
        oa3.x=fmaf(p3,v0.x,oa3.x); oa3.y=fmaf(p3,v0.y,oa3.y); oa3.z=fmaf(p3,v0.z,oa3.z); oa3.w=fmaf(p3,v0.w,oa3.w);
        ob3.x=fmaf(p3,v1.x,ob3.x); ob3.y=fmaf(p3,v1.y,ob3.y); ob3.z=fmaf(p3,v1.z,ob3.z); ob3.w=fmaf(p3,v1.w,ob3.w);
    }
    RBAR();   // all p reads done; sbuf reusable as partial buffer

    // reduce over the 16 column-groups (lanes differing in bits 2..5)
    #pragma unroll
    for (int d2 = 4; d2 <= 32; d2 <<= 1) {
        oa0.x+=__shfl_xor(oa0.x,d2); oa0.y+=__shfl_xor(oa0.y,d2); oa0.z+=__shfl_xor(oa0.z,d2); oa0.w+=__shfl_xor(oa0.w,d2);
        ob0.x+=__shfl_xor(ob0.x,d2); ob0.y+=__shfl_xor(ob0.y,d2); ob0.z+=__shfl_xor(ob0.z,d2); ob0.w+=__shfl_xor(ob0.w,d2);
        oa1.x+=__shfl_xor(oa1.x,d2); oa1.y+=__shfl_xor(oa1.y,d2); oa1.z+=__shfl_xor(oa1.z,d2); oa1.w+=__shfl_xor(oa1.w,d2);
        ob1.x+=__shfl_xor(ob1.x,d2); ob1.y+=__shfl_xor(ob1.y,d2); ob1.z+=__shfl_xor(ob1.z,d2); ob1.w+=__shfl_xor(ob1.w,d2);
        oa2.x+=__shfl_xor(oa2.x,d2); oa2.y+=__shfl_xor(oa2.y,d2); oa2.z+=__shfl_xor(oa2.z,d2); oa2.w+=__shfl_xor(oa2.w,d2);
        ob2.x+=__shfl_xor(ob2.x,d2); ob2.y+=__shfl_xor(ob2.y,d2); ob2.z+=__shfl_xor(ob2.z,d2); ob2.w+=__shfl_xor(ob2.w,d2);
        oa3.x+=__shfl_xor(oa3.x,d2); oa3.y+=__shfl_xor(oa3.y,d2); oa3.z+=__shfl_xor(oa3.z,d2); oa3.w+=__shfl_xor(oa3.w,d2);
        ob3.x+=__shfl_xor(ob3.x,d2); ob3.y+=__shfl_xor(ob3.y,d2); ob3.z+=__shfl_xor(ob3.z,d2); ob3.w+=__shfl_xor(ob3.w,d2);
    }
    // lanes 0..3 of each wave hold dim-chunk l for all 4 rows
    if (l < 4) {
        float* part = &sbuf[0];   // [4 waves][4 rows][32 dims]
        *(float4*)&part[(w * 4 + 0) * 32 + l * 8]     = oa0;
        *(float4*)&part[(w * 4 + 0) * 32 + l * 8 + 4] = ob0;
        *(float4*)&part[(w * 4 + 1) * 32 + l * 8]     = oa1;
        *(float4*)&part[(w * 4 + 1) * 32 + l * 8 + 4] = ob1;
        *(float4*)&part[(w * 4 + 2) * 32 + l * 8]     = oa2;
        *(float4*)&part[(w * 4 + 2) * 32 + l * 8 + 4] = ob2;
        *(float4*)&part[(w * 4 + 3) * 32 + l * 8]     = oa3;
        *(float4*)&part[(w * 4 + 3) * 32 + l * 8 + 4] = ob3;
    }
    RBAR();
    if (tid < 128) {
        const int r = tid >> 5, d = tid & 31;
        const float* part = &sbuf[0];
        float o = part[(0 * 4 + r) * 32 + d] + part[(1 * 4 + r) * 32 + d]
                + part[(2 * 4 + r) * 32 + d] + part[(3 * 4 + r) * 32 + d];
        o /= zS[r];
        aout[((size_t)b * NSEQ + n0 + r) * CDIM + h * 32 + d] = o;
    }
}

// -------------------------------------------------------------------------
extern "C" void kernel_launch(void* const* d_in, const int* in_sizes, int n_in,
                              void* d_out, int out_size, void* d_ws, size_t ws_size,
                              hipStream_t stream) {
    (void)in_sizes; (void)n_in; (void)out_size; (void)ws_size;
    const float* x      = (const float*)d_in[0];
    const float* w_qkv  = (const float*)d_in[1];
    const float* b_qkv  = (const float*)d_in[2];
    const float* w_proj = (const float*)d_in[3];
    const float* b_proj = (const float*)d_in[4];
    float* out = (float*)d_out;

    const int M = BDIM * NSEQ;  // 8192
    float* qkv_ws  = (float*)d_ws;                       // 25.2 MB
    float* attn_ws = qkv_ws + (size_t)M * 768;           // 8.4 MB

    // 1) QKV GEMM -> [B][N][3][H][D]
    dim3 g1(M / 64, 768 / 64);
    gemm_nt_bias<<<g1, 256, 0, stream>>>(x, w_qkv, b_qkv, qkv_ws, M, 768, 256);

    // 2) fused sparse attention -> [B][N][C]
    sparse_attn<<<BDIM * NHEADS * (NSEQ / QB), 256, 0, stream>>>(qkv_ws, attn_ws);

    // 3) projection GEMM -> d_out
    dim3 g2(M / 64, 256 / 64);
    gemm_nt_bias<<<g2, 256, 0, stream>>>(attn_ws, w_proj, b_proj, out, M, 256, 256);
}

// Round 7
// 864.829 us; speedup vs baseline: 1.8440x; 1.8440x over previous
//
#include <hip/hip_runtime.h>

// Problem constants (B=4, N=2048, C=256, H=8, D=32, keep = int(2048*0.3) = 614)
#define BDIM 4
#define NSEQ 2048
#define CDIM 256
#define NHEADS 8
#define QB 4                     // query rows per block (1 per wave)
#define NT2 32                   // per-wave tiles: 32 tiles x 16 rows = 512 cols
#define NKEEP 614                // int(2048 * (1.0 - 0.7))
#define ATTN_SCALE 0.17677669529663688f  // 32^-0.5

// -------------------------------------------------------------------------
// GEMM: C[M][Nt] = A[M][K] @ W[Nt][K]^T + bias[Nt]   (unchanged, validated)
// -------------------------------------------------------------------------
__global__ __launch_bounds__(256) void gemm_nt_bias(
    const float* __restrict__ A, const float* __restrict__ W,
    const float* __restrict__ bias, float* __restrict__ C,
    int M, int Nt, int K)
{
    __shared__ __align__(16) float As[32][68];
    __shared__ __align__(16) float Ws[32][68];
    const int tid = threadIdx.x;
    const int bm = blockIdx.x * 64;
    const int bn = blockIdx.y * 64;
    const int tm = tid >> 4;
    const int tn = tid & 15;
    const int lr = tid >> 2;
    const int lq = tid & 3;
    const float* Ap = A + (size_t)(bm + lr) * K + lq * 8;
    const float* Wp = W + (size_t)(bn + lr) * K + lq * 8;
    float acc[4][4] = {};

    for (int k0 = 0; k0 < K; k0 += 32) {
        float4 a0 = *(const float4*)(Ap + k0);
        float4 a1 = *(const float4*)(Ap + k0 + 4);
        float4 w0 = *(const float4*)(Wp + k0);
        float4 w1 = *(const float4*)(Wp + k0 + 4);
        __syncthreads();
        const int kq = lq * 8;
        As[kq+0][lr]=a0.x; As[kq+1][lr]=a0.y; As[kq+2][lr]=a0.z; As[kq+3][lr]=a0.w;
        As[kq+4][lr]=a1.x; As[kq+5][lr]=a1.y; As[kq+6][lr]=a1.z; As[kq+7][lr]=a1.w;
        Ws[kq+0][lr]=w0.x; Ws[kq+1][lr]=w0.y; Ws[kq+2][lr]=w0.z; Ws[kq+3][lr]=w0.w;
        Ws[kq+4][lr]=w1.x; Ws[kq+5][lr]=w1.y; Ws[kq+6][lr]=w1.z; Ws[kq+7][lr]=w1.w;
        __syncthreads();
        #pragma unroll
        for (int k = 0; k < 32; ++k) {
            float4 av = *(const float4*)&As[k][tm*4];
            float4 wv = *(const float4*)&Ws[k][tn*4];
            acc[0][0] += av.x*wv.x; acc[0][1] += av.x*wv.y; acc[0][2] += av.x*wv.z; acc[0][3] += av.x*wv.w;
            acc[1][0] += av.y*wv.x; acc[1][1] += av.y*wv.y; acc[1][2] += av.y*wv.z; acc[1][3] += av.y*wv.w;
            acc[2][0] += av.z*wv.x; acc[2][1] += av.z*wv.y; acc[2][2] += av.z*wv.z; acc[2][3] += av.z*wv.w;
            acc[3][0] += av.w*wv.x; acc[3][1] += av.w*wv.y; acc[3][2] += av.w*wv.z; acc[3][3] += av.w*wv.w;
        }
    }
    float4 bb = *(const float4*)(bias + bn + tn*4);
    #pragma unroll
    for (int i = 0; i < 4; ++i) {
        float4 o;
        o.x = acc[i][0] + bb.x;
        o.y = acc[i][1] + bb.y;
        o.z = acc[i][2] + bb.z;
        o.w = acc[i][3] + bb.w;
        *(float4*)(C + (size_t)(bm + tm*4 + i) * Nt + bn + tn*4) = o;
    }
}

// -------------------------------------------------------------------------
// Fused sparse attention — per-wave barrier-free streaming.
// Wave w privately streams K/V columns [512w, 512w+512) in 16-row tiles
// through its own double-buffered LDS ring (per-wave vmcnt/lgkm waits only;
// no block barriers in the streaming loops). Each wave computes scores for
// all 4 q-rows at its columns (quad-DPP reduce); radix/softmax per-row per
// wave. Only 5 block barriers total.
// -------------------------------------------------------------------------
__device__ __forceinline__ unsigned int f2key(float f) {
    unsigned int u = __float_as_uint(f);
    return (u & 0x80000000u) ? ~u : (u | 0x80000000u);  // monotone order-preserving
}

// cross-lane add within quad: xor1 = quad_perm(1,0,3,2)=0xB1, xor2 = (2,3,0,1)=0x4E
__device__ __forceinline__ float dpp_xor1_add(float x) {
    int s = __builtin_amdgcn_mov_dpp(__float_as_int(x), 0xB1, 0xF, 0xF, true);
    return x + __int_as_float(s);
}
__device__ __forceinline__ float dpp_xor2_add(float x) {
    int s = __builtin_amdgcn_mov_dpp(__float_as_int(x), 0x4E, 0xF, 0xF, true);
    return x + __int_as_float(s);
}

typedef __attribute__((address_space(1))) const void gas_void;
typedef __attribute__((address_space(3))) void las_void;

__device__ __forceinline__ void gload_lds16(const float* g, float4* l) {
    __builtin_amdgcn_global_load_lds((gas_void*)g, (las_void*)l, 16, 0, 0);
}

// stage 16 rows x 32 floats (global row stride 768) into per-wave dst4[128].
// LDS slot s holds global (row=s>>3, chunk=(s&7)^(row&7)); 2 wave-instrs.
__device__ __forceinline__ void stage16(const float* __restrict__ g, float4* dst4, int l) {
    const int s0 = l, s1 = l + 64;
    const int r0 = s0 >> 3, c0 = (s0 & 7) ^ (r0 & 7);
    const int r1 = s1 >> 3, c1 = (s1 & 7) ^ (r1 & 7);
    gload_lds16(g + (size_t)r0 * 768 + c0 * 4, dst4 + s0);
    gload_lds16(g + (size_t)r1 * 768 + c1 * 4, dst4 + s1);
}

// raw barrier: drain LDS ops, do NOT drain vmcnt (keeps prefetch in flight)
#define RBAR() do { asm volatile("s_waitcnt lgkmcnt(0)" ::: "memory"); \
                    __builtin_amdgcn_s_barrier();                      \
                    asm volatile("" ::: "memory"); } while (0)
#define LGKM0() asm volatile("s_waitcnt lgkmcnt(0)" ::: "memory")
// per-wave counted wait: tile t's 2 loads landed; next tile's 2 stay in flight
#define VMW(t, last) do { if ((t) < (last)) asm volatile("s_waitcnt vmcnt(2)" ::: "memory"); \
                          else              asm volatile("s_waitcnt vmcnt(0)" ::: "memory"); } while (0)

__global__ __launch_bounds__(256, 3) void sparse_attn(
    const float* __restrict__ qkv, float* __restrict__ aout)
{
    __shared__ __align__(16) float4 ring[4][2][128];   // per-wave 2x2KB ring, 16 KB
    __shared__ __align__(16) float  sbuf[QB * NSEQ];   // 32 KB scores / p-values
    __shared__ __align__(16) unsigned int hist[QB * 256]; // 4 KB
    __shared__ unsigned int prefS[QB];
    __shared__ int   remS[QB];
    __shared__ float zS[QB];

    const int tid = threadIdx.x;
    const int w   = tid >> 6;       // wave id = row id (0..3) = column-range owner
    const int l   = tid & 63;
    const int p   = l & 3;          // dim-chunk pair (8 floats at 8p)
    const int jg  = l >> 2;         // 0..15 = tile row/column index
    const int sw1 = (2 * p)     ^ (jg & 7);
    const int sw2 = (2 * p + 1) ^ (jg & 7);

    const int blk = blockIdx.x;
    const int nqb = NSEQ / QB;      // 512
    const int bh  = blk / nqb;
    const int qblk = blk % nqb;
    const int b = bh / NHEADS, h = bh % NHEADS;
    const int n0 = qblk * QB;

    const float* base = qkv + (size_t)b * NSEQ * 768;
    const float* gkw = base + 256 + h * 32 + (size_t)(512 * w) * 768;  // wave's K cols
    const float* gvw = base + 512 + h * 32 + (size_t)(512 * w) * 768;  // wave's V cols

    // ---- Q rows 0..3, this lane's 8-dim chunk, pre-scaled, in registers ----
    float4 qa[QB], qc[QB];
    {
        const float* gq = base + (size_t)n0 * 768 + h * 32 + p * 8;
        #pragma unroll
        for (int r = 0; r < QB; ++r) {
            float4 x0 = *(const float4*)(gq + (size_t)r * 768);
            float4 x1 = *(const float4*)(gq + (size_t)r * 768 + 4);
            qa[r].x = x0.x * ATTN_SCALE; qa[r].y = x0.y * ATTN_SCALE;
            qa[r].z = x0.z * ATTN_SCALE; qa[r].w = x0.w * ATTN_SCALE;
            qc[r].x = x1.x * ATTN_SCALE; qc[r].y = x1.y * ATTN_SCALE;
            qc[r].z = x1.z * ATTN_SCALE; qc[r].w = x1.w * ATTN_SCALE;
        }
    }
    // zero pass-3 histogram (filled inline during phase B by all waves)
    {
        uint4 z4; z4.x = 0u; z4.y = 0u; z4.z = 0u; z4.w = 0u;
        *(uint4*)(hist + tid * 4) = z4;
    }
    if (tid < QB) { prefS[tid] = 0u; remS[tid] = NKEEP; }
    RBAR();   // barrier 1: hist/prefS initialized before any atomic

    // ---- Phase B: scores + top-byte histogram. Per-wave, barrier-free. ----
    stage16(gkw,                     &ring[w][0][0], l);
    stage16(gkw + (size_t)16 * 768,  &ring[w][1][0], l);
    #pragma unroll 1
    for (int t = 0; t < NT2; ++t) {
        VMW(t, NT2 - 1);                       // my tile t landed
        float4* kb = &ring[w][t & 1][0];
        float4 k0 = kb[jg * 8 + sw1];
        float4 k1 = kb[jg * 8 + sw2];
        LGKM0();                               // reads in regs before overwrite
        if (t + 2 < NT2) stage16(gkw + (size_t)(16 * (t + 2)) * 768, kb, l);
        float sc0 = qa[0].x*k0.x + qa[0].y*k0.y + qa[0].z*k0.z + qa[0].w*k0.w
                  + qc[0].x*k1.x + qc[0].y*k1.y + qc[0].z*k1.z + qc[0].w*k1.w;
        float sc1 = qa[1].x*k0.x + qa[1].y*k0.y + qa[1].z*k0.z + qa[1].w*k0.w
                  + qc[1].x*k1.x + qc[1].y*k1.y + qc[1].z*k1.z + qc[1].w*k1.w;
        float sc2 = qa[2].x*k0.x + qa[2].y*k0.y + qa[2].z*k0.z + qa[2].w*k0.w
                  + qc[2].x*k1.x + qc[2].y*k1.y + qc[2].z*k1.z + qc[2].w*k1.w;
        float sc3 = qa[3].x*k0.x + qa[3].y*k0.y + qa[3].z*k0.z + qa[3].w*k0.w
                  + qc[3].x*k1.x + qc[3].y*k1.y + qc[3].z*k1.z + qc[3].w*k1.w;
        sc0 = dpp_xor2_add(dpp_xor1_add(sc0));
        sc1 = dpp_xor2_add(dpp_xor1_add(sc1));
        sc2 = dpp_xor2_add(dpp_xor1_add(sc2));
        sc3 = dpp_xor2_add(dpp_xor1_add(sc3));
        float myv = (p == 0) ? sc0 : (p == 1) ? sc1 : (p == 2) ? sc2 : sc3;
        const int col = (w << 9) + (t << 4) + jg;
        sbuf[p * NSEQ + col] = myv;
        atomicAdd(&hist[p * 256 + (f2key(myv) >> 24)], 1u);  // radix pass 3 inline
    }
    // ring is private: stage V tiles 0,1 now; they fly across select/softmax
    stage16(gvw,                    &ring[w][0][0], l);
    stage16(gvw + (size_t)16 * 768, &ring[w][1][0], l);
    RBAR();   // barrier 2: all scores + histogram atomics visible

    // ---- Phase C: exact 614th-largest per row. Wave w owns row w only. ----
    unsigned int* hrow = hist + w * 256;
    #pragma unroll 1
    for (int pass = 3; pass >= 0; --pass) {
        const int sh = pass * 8;
        const unsigned int pr = prefS[w];
        const int remv = remS[w];
        if (pass != 3) {
            const unsigned int hmsk = 0xFFFFFFFFu << (sh + 8);
            uint4 z4; z4.x = 0u; z4.y = 0u; z4.z = 0u; z4.w = 0u;
            *(uint4*)(hrow + l * 4) = z4;
            LGKM0();
            #pragma unroll 2
            for (int e = 0; e < 8; ++e) {
                float4 v = *(const float4*)&sbuf[w * NSEQ + l * 4 + 256 * e];
                unsigned int k0 = f2key(v.x), k1 = f2key(v.y), k2 = f2key(v.z), k3 = f2key(v.w);
                if ((k0 & hmsk) == pr) atomicAdd(&hrow[(k0 >> sh) & 255u], 1u);
                if ((k1 & hmsk) == pr) atomicAdd(&hrow[(k1 >> sh) & 255u], 1u);
                if ((k2 & hmsk) == pr) atomicAdd(&hrow[(k2 >> sh) & 255u], 1u);
                if ((k3 & hmsk) == pr) atomicAdd(&hrow[(k3 >> sh) & 255u], 1u);
            }
            LGKM0();
        }
        uint4 c4 = *(const uint4*)(hrow + l * 4);
        unsigned int cnt[4] = { c4.x, c4.y, c4.z, c4.w };
        unsigned int part = cnt[0] + cnt[1] + cnt[2] + cnt[3];
        unsigned int suf = part;
        #pragma unroll
        for (int dlt = 1; dlt < 64; dlt <<= 1) {
            unsigned int v = __shfl_down(suf, dlt);
            if (l + dlt < 64) suf += v;
        }
        unsigned int run = suf - part;   // elems in bins owned by lanes > l
        #pragma unroll
        for (int i = 3; i >= 0; --i) {
            if ((int)run < remv && remv <= (int)(run + cnt[i])) {
                remS[w]  = remv - (int)run;
                prefS[w] = pr | ((unsigned int)(l * 4 + i) << sh);
            }
            run += cnt[i];
        }
        LGKM0();  // pref/rem visible wave-wide before next pass
    }

    // ---- Phase D: masked softmax on row w (float4, in LDS) ----
    {
        unsigned int key = prefS[w];
        unsigned int u = (key & 0x80000000u) ? (key & 0x7FFFFFFFu) : ~key;
        const float thr = __uint_as_float(u);
        float mx = 0.f;   // >=1434 masked zeros always present
        #pragma unroll 2
        for (int e = 0; e < 8; ++e) {
            float* sp = &sbuf[w * NSEQ + l * 4 + 256 * e];
            float4 v = *(const float4*)sp;
            v.x = (v.x >= thr) ? v.x : 0.f;
            v.y = (v.y >= thr) ? v.y : 0.f;
            v.z = (v.z >= thr) ? v.z : 0.f;
            v.w = (v.w >= thr) ? v.w : 0.f;
            *(float4*)sp = v;
            mx = fmaxf(mx, fmaxf(fmaxf(v.x, v.y), fmaxf(v.z, v.w)));
        }
        #pragma unroll
        for (int d2 = 32; d2 >= 1; d2 >>= 1) mx = fmaxf(mx, __shfl_xor(mx, d2));
        float Z = 0.f;
        #pragma unroll 2
        for (int e = 0; e < 8; ++e) {
            float* sp = &sbuf[w * NSEQ + l * 4 + 256 * e];
            float4 v = *(const float4*)sp;
            v.x = __expf(v.x - mx); v.y = __expf(v.y - mx);
            v.z = __expf(v.z - mx); v.w = __expf(v.w - mx);
            *(float4*)sp = v;
            Z += v.x + v.y + v.z + v.w;
        }
        #pragma unroll
        for (int d2 = 32; d2 >= 1; d2 >>= 1) Z += __shfl_xor(Z, d2);
        if (l == 0) zS[w] = Z;
    }
    RBAR();   // barrier 3: all rows' p-values + zS visible

    // ---- Phase E: PV. Per-wave streaming over its V columns, no barriers. ----
    float4 oa0, oa1, oa2, oa3, ob0, ob1, ob2, ob3;
    oa0.x=0;oa0.y=0;oa0.z=0;oa0.w=0; ob0=oa0; oa1=oa0; ob1=oa0;
    oa2=oa0; ob2=oa0; oa3=oa0; ob3=oa0;
    #pragma unroll 1
    for (int t = 0; t < NT2; ++t) {
        VMW(t, NT2 - 1);
        float4* vb = &ring[w][t & 1][0];
        float4 v0 = vb[jg * 8 + sw1];
        float4 v1 = vb[jg * 8 + sw2];
        LGKM0();
        if (t + 2 < NT2) stage16(gvw + (size_t)(16 * (t + 2)) * 768, vb, l);
        const int col = (w << 9) + (t << 4) + jg;
        float p0 = sbuf[0 * NSEQ + col];
        float p1 = sbuf[1 * NSEQ + col];
        float p2 = sbuf[2 * NSEQ + col];
        float p3 = sbuf[3 * NSEQ + col];
        oa0.x=fmaf(p0,v0.x,oa0.x); oa0.y=fmaf(p0,v0.y,oa0.y); oa0.z=fmaf(p0,v0.z,oa0.z); oa0.w=fmaf(p0,v0.w,oa0.w);
        ob0.x=fmaf(p0,v1.x,ob0.x); ob0.y=fmaf(p0,v1.y,ob0.y); ob0.z=fmaf(p0,v1.z,ob0.z); ob0.w=fmaf(p0,v1.w,ob0.w);
        oa1.x=fmaf(p1,v0.x,oa1.x); oa1.y=fmaf(p1,v0.y,oa1.y); oa1.z=fmaf(p1,v0.z,oa1.z); oa1.w=fmaf(p1,v0.w,oa1.w);
        ob1.x=fmaf(p1,v1.x,ob1.x); ob1.y=fmaf(p1,v1.y,ob1.y); ob1.z=fmaf(p1,v1.z,ob1.z); ob1.w=fmaf(p1,v1.w,ob1.w);
        oa2.x=fmaf(p2,v0.x,oa2.x); oa2.y=fmaf(p2,v0.y,oa2.y); oa2.z=fmaf(p2,v0.z,oa2.z); oa2.w=fmaf(p2,v0.w,oa2.w);
        ob2.x=fmaf(p2,v1.x,ob2.x); ob2.y=fmaf(p2,v1.y,ob2.y); ob2.z=fmaf(p2,v1.z,ob2.z); ob2.w=fmaf(p2,v1.w,ob2.w);
        oa3.x=fmaf(p3,v0.x,oa3.x); oa3.y=fmaf(p3,v0.y,oa3.y); oa3.z=fmaf(p3,v0.z,oa3.z); oa3.w=fmaf(p3,v0.w,oa3.w);
        ob3.x=fmaf(p3,v1.x,ob3.x); ob3.y=fmaf(p3,v1.y,ob3.y); ob3.z=fmaf(p3,v1.z,ob3.z); ob3.w=fmaf(p3,v1.w,ob3.w);
    }
    RBAR();   // barrier 4: all p-value reads done; sbuf reusable as partials

    // reduce over the 16 column-groups (lanes differing in bits 2..5)
    #pragma unroll
    for (int d2 = 4; d2 <= 32; d2 <<= 1) {
        oa0.x+=__shfl_xor(oa0.x,d2); oa0.y+=__shfl_xor(oa0.y,d2); oa0.z+=__shfl_xor(oa0.z,d2); oa0.w+=__shfl_xor(oa0.w,d2);
        ob0.x+=__shfl_xor(ob0.x,d2); ob0.y+=__shfl_xor(ob0.y,d2); ob0.z+=__shfl_xor(ob0.z,d2); ob0.w+=__shfl_xor(ob0.w,d2);
        oa1.x+=__shfl_xor(oa1.x,d2); oa1.y+=__shfl_xor(oa1.y,d2); oa1.z+=__shfl_xor(oa1.z,d2); oa1.w+=__shfl_xor(oa1.w,d2);
        ob1.x+=__shfl_xor(ob1.x,d2); ob1.y+=__shfl_xor(ob1.y,d2); ob1.z+=__shfl_xor(ob1.z,d2); ob1.w+=__shfl_xor(ob1.w,d2);
        oa2.x+=__shfl_xor(oa2.x,d2); oa2.y+=__shfl_xor(oa2.y,d2); oa2.z+=__shfl_xor(oa2.z,d2); oa2.w+=__shfl_xor(oa2.w,d2);
        ob2.x+=__shfl_xor(ob2.x,d2); ob2.y+=__shfl_xor(ob2.y,d2); ob2.z+=__shfl_xor(ob2.z,d2); ob2.w+=__shfl_xor(ob2.w,d2);
        oa3.x+=__shfl_xor(oa3.x,d2); oa3.y+=__shfl_xor(oa3.y,d2); oa3.z+=__shfl_xor(oa3.z,d2); oa3.w+=__shfl_xor(oa3.w,d2);
        ob3.x+=__shfl_xor(ob3.x,d2); ob3.y+=__shfl_xor(ob3.y,d2); ob3.z+=__shfl_xor(ob3.z,d2); ob3.w+=__shfl_xor(ob3.w,d2);
    }
    // lanes 0..3 of each wave hold dim-chunk l (=p) for all 4 rows
    if (l < 4) {
        float* part = &sbuf[0];   // [4 waves][4 rows][32 dims]
        *(float4*)&part[(w * 4 + 0) * 32 + l * 8]     = oa0;
        *(float4*)&part[(w * 4 + 0) * 32 + l * 8 + 4] = ob0;
        *(float4*)&part[(w * 4 + 1) * 32 + l * 8]     = oa1;
        *(float4*)&part[(w * 4 + 1) * 32 + l * 8 + 4] = ob1;
        *(float4*)&part[(w * 4 + 2) * 32 + l * 8]     = oa2;
        *(float4*)&part[(w * 4 + 2) * 32 + l * 8 + 4] = ob2;
        *(float4*)&part[(w * 4 + 3) * 32 + l * 8]     = oa3;
        *(float4*)&part[(w * 4 + 3) * 32 + l * 8 + 4] = ob3;
    }
    RBAR();   // barrier 5
    if (tid < 128) {
        const int r = tid >> 5, d = tid & 31;
        const float* part = &sbuf[0];
        float o = part[(0 * 4 + r) * 32 + d] + part[(1 * 4 + r) * 32 + d]
                + part[(2 * 4 + r) * 32 + d] + part[(3 * 4 + r) * 32 + d];
        o /= zS[r];
        aout[((size_t)b * NSEQ + n0 + r) * CDIM + h * 32 + d] = o;
    }
}

// -------------------------------------------------------------------------
extern "C" void kernel_launch(void* const* d_in, const int* in_sizes, int n_in,
                              void* d_out, int out_size, void* d_ws, size_t ws_size,
                              hipStream_t stream) {
    (void)in_sizes; (void)n_in; (void)out_size; (void)ws_size;
    const float* x      = (const float*)d_in[0];
    const float* w_qkv  = (const float*)d_in[1];
    const float* b_qkv  = (const float*)d_in[2];
    const float* w_proj = (const float*)d_in[3];
    const float* b_proj = (const float*)d_in[4];
    float* out = (float*)d_out;

    const int M = BDIM * NSEQ;  // 8192
    float* qkv_ws  = (float*)d_ws;                       // 25.2 MB
    float* attn_ws = qkv_ws + (size_t)M * 768;           // 8.4 MB

    // 1) QKV GEMM -> [B][N][3][H][D]
    dim3 g1(M / 64, 768 / 64);
    gemm_nt_bias<<<g1, 256, 0, stream>>>(x, w_qkv, b_qkv, qkv_ws, M, 768, 256);

    // 2) fused sparse attention -> [B][N][C]
    sparse_attn<<<BDIM * NHEADS * (NSEQ / QB), 256, 0, stream>>>(qkv_ws, attn_ws);

    // 3) projection GEMM -> d_out
    dim3 g2(M / 64, 256 / 64);
    gemm_nt_bias<<<g2, 256, 0, stream>>>(attn_ws, w_proj, b_proj, out, M, 256, 256);
}

// Round 8
// 667.200 us; speedup vs baseline: 2.3902x; 1.2962x over previous
//
#include <hip/hip_runtime.h>

// Problem constants (B=4, N=2048, C=256, H=8, D=32, keep = int(2048*0.3) = 614)
#define BDIM 4
#define NSEQ 2048
#define CDIM 256
#define NHEADS 8
#define QB 4                     // query rows per block (1 per wave)
#define NT2 32                   // per-wave tiles: 32 tiles x 16 rows = 512 cols
#define NKEEP 614                // int(2048 * (1.0 - 0.7))
#define SSTR 2056                // sbuf row stride (bank stagger: 2056%32 = 8)
#define ATTN_SCALE 0.17677669529663688f  // 32^-0.5

// -------------------------------------------------------------------------
// GEMM: C[M][Nt] = A[M][K] @ W[Nt][K]^T + bias[Nt]   (unchanged, validated)
// -------------------------------------------------------------------------
__global__ __launch_bounds__(256) void gemm_nt_bias(
    const float* __restrict__ A, const float* __restrict__ W,
    const float* __restrict__ bias, float* __restrict__ C,
    int M, int Nt, int K)
{
    __shared__ __align__(16) float As[32][68];
    __shared__ __align__(16) float Ws[32][68];
    const int tid = threadIdx.x;
    const int bm = blockIdx.x * 64;
    const int bn = blockIdx.y * 64;
    const int tm = tid >> 4;
    const int tn = tid & 15;
    const int lr = tid >> 2;
    const int lq = tid & 3;
    const float* Ap = A + (size_t)(bm + lr) * K + lq * 8;
    const float* Wp = W + (size_t)(bn + lr) * K + lq * 8;
    float acc[4][4] = {};

    for (int k0 = 0; k0 < K; k0 += 32) {
        float4 a0 = *(const float4*)(Ap + k0);
        float4 a1 = *(const float4*)(Ap + k0 + 4);
        float4 w0 = *(const float4*)(Wp + k0);
        float4 w1 = *(const float4*)(Wp + k0 + 4);
        __syncthreads();
        const int kq = lq * 8;
        As[kq+0][lr]=a0.x; As[kq+1][lr]=a0.y; As[kq+2][lr]=a0.z; As[kq+3][lr]=a0.w;
        As[kq+4][lr]=a1.x; As[kq+5][lr]=a1.y; As[kq+6][lr]=a1.z; As[kq+7][lr]=a1.w;
        Ws[kq+0][lr]=w0.x; Ws[kq+1][lr]=w0.y; Ws[kq+2][lr]=w0.z; Ws[kq+3][lr]=w0.w;
        Ws[kq+4][lr]=w1.x; Ws[kq+5][lr]=w1.y; Ws[kq+6][lr]=w1.z; Ws[kq+7][lr]=w1.w;
        __syncthreads();
        #pragma unroll
        for (int k = 0; k < 32; ++k) {
            float4 av = *(const float4*)&As[k][tm*4];
            float4 wv = *(const float4*)&Ws[k][tn*4];
            acc[0][0] += av.x*wv.x; acc[0][1] += av.x*wv.y; acc[0][2] += av.x*wv.z; acc[0][3] += av.x*wv.w;
            acc[1][0] += av.y*wv.x; acc[1][1] += av.y*wv.y; acc[1][2] += av.y*wv.z; acc[1][3] += av.y*wv.w;
            acc[2][0] += av.z*wv.x; acc[2][1] += av.z*wv.y; acc[2][2] += av.z*wv.z; acc[2][3] += av.z*wv.w;
            acc[3][0] += av.w*wv.x; acc[3][1] += av.w*wv.y; acc[3][2] += av.w*wv.z; acc[3][3] += av.w*wv.w;
        }
    }
    float4 bb = *(const float4*)(bias + bn + tn*4);
    #pragma unroll
    for (int i = 0; i < 4; ++i) {
        float4 o;
        o.x = acc[i][0] + bb.x;
        o.y = acc[i][1] + bb.y;
        o.z = acc[i][2] + bb.z;
        o.w = acc[i][3] + bb.w;
        *(float4*)(C + (size_t)(bm + tm*4 + i) * Nt + bn + tn*4) = o;
    }
}

// -------------------------------------------------------------------------
// Fused sparse attention — per-wave streaming, K/V direct global->register.
// Wave w privately streams K/V columns [512w, 512w+512) in 16-row tiles,
// 2-tile register ping-pong (no LDS staging at all). Scores in LDS.
// Only 5 block barriers total.
// -------------------------------------------------------------------------
__device__ __forceinline__ unsigned int f2key(float f) {
    unsigned int u = __float_as_uint(f);
    return (u & 0x80000000u) ? ~u : (u | 0x80000000u);  // monotone order-preserving
}

// cross-lane add within quad: xor1 = quad_perm(1,0,3,2)=0xB1, xor2 = (2,3,0,1)=0x4E
__device__ __forceinline__ float dpp_xor1_add(float x) {
    int s = __builtin_amdgcn_mov_dpp(__float_as_int(x), 0xB1, 0xF, 0xF, true);
    return x + __int_as_float(s);
}
__device__ __forceinline__ float dpp_xor2_add(float x) {
    int s = __builtin_amdgcn_mov_dpp(__float_as_int(x), 0x4E, 0xF, 0xF, true);
    return x + __int_as_float(s);
}

// raw barrier: drain LDS ops, do NOT drain vmcnt (keeps prefetch in flight)
#define RBAR() do { asm volatile("s_waitcnt lgkmcnt(0)" ::: "memory"); \
                    __builtin_amdgcn_s_barrier();                      \
                    asm volatile("" ::: "memory"); } while (0)
#define LGKM0() asm volatile("s_waitcnt lgkmcnt(0)" ::: "memory")

__global__ __launch_bounds__(256, 4) void sparse_attn(
    const float* __restrict__ qkv, float* __restrict__ aout)
{
    __shared__ __align__(16) float  sbuf[QB * SSTR];        // 32.1 KB scores / p-values
    __shared__ __align__(16) unsigned int hist[QB * 256];   // 4 KB
    __shared__ unsigned int prefS[QB];
    __shared__ int   remS[QB];
    __shared__ float zS[QB];

    const int tid = threadIdx.x;
    const int w   = tid >> 6;       // wave id = row id (0..3) = column-range owner
    const int l   = tid & 63;
    const int p   = l & 3;          // dim-chunk pair (8 floats at 8p)
    const int jg  = l >> 2;         // 0..15 = row within a 16-row tile

    const int blk = blockIdx.x;
    const int nqb = NSEQ / QB;      // 512
    const int bh  = blk / nqb;
    const int qblk = blk % nqb;
    const int b = bh / NHEADS, h = bh % NHEADS;
    const int n0 = qblk * QB;

    const float* base = qkv + (size_t)b * NSEQ * 768;
    // this thread's K/V column pointers: column = 512w + t*16 + jg, dims [8p, 8p+8)
    const float* kptr = base + 256 + h * 32 + p * 8 + (size_t)((w << 9) + jg) * 768;
    const float* vptr = base + 512 + h * 32 + p * 8 + (size_t)((w << 9) + jg) * 768;
#define KADDR(t) (kptr + (size_t)(t) * (16 * 768))
#define VADDR(t) (vptr + (size_t)(t) * (16 * 768))

    // ---- Q rows 0..3, this lane's 8-dim chunk, pre-scaled, in registers ----
    float4 qa[QB], qc[QB];
    {
        const float* gq = base + (size_t)n0 * 768 + h * 32 + p * 8;
        #pragma unroll
        for (int r = 0; r < QB; ++r) {
            float4 x0 = *(const float4*)(gq + (size_t)r * 768);
            float4 x1 = *(const float4*)(gq + (size_t)r * 768 + 4);
            qa[r].x = x0.x * ATTN_SCALE; qa[r].y = x0.y * ATTN_SCALE;
            qa[r].z = x0.z * ATTN_SCALE; qa[r].w = x0.w * ATTN_SCALE;
            qc[r].x = x1.x * ATTN_SCALE; qc[r].y = x1.y * ATTN_SCALE;
            qc[r].z = x1.z * ATTN_SCALE; qc[r].w = x1.w * ATTN_SCALE;
        }
    }
    // zero pass-3 histogram (filled inline during phase B by all waves)
    {
        uint4 z4; z4.x = 0u; z4.y = 0u; z4.z = 0u; z4.w = 0u;
        *(uint4*)(hist + tid * 4) = z4;
    }
    if (tid < QB) { prefS[tid] = 0u; remS[tid] = NKEEP; }
    RBAR();   // barrier 1: hist/prefS initialized before any atomic

    // per-tile score computation: K/V chunk regs -> 4 row scores -> sbuf + hist
#define QK_TILE(K0, K1, T) do {                                               \
        float sc0 = qa[0].x*(K0).x + qa[0].y*(K0).y + qa[0].z*(K0).z + qa[0].w*(K0).w \
                  + qc[0].x*(K1).x + qc[0].y*(K1).y + qc[0].z*(K1).z + qc[0].w*(K1).w; \
        float sc1 = qa[1].x*(K0).x + qa[1].y*(K0).y + qa[1].z*(K0).z + qa[1].w*(K0).w \
                  + qc[1].x*(K1).x + qc[1].y*(K1).y + qc[1].z*(K1).z + qc[1].w*(K1).w; \
        float sc2 = qa[2].x*(K0).x + qa[2].y*(K0).y + qa[2].z*(K0).z + qa[2].w*(K0).w \
                  + qc[2].x*(K1).x + qc[2].y*(K1).y + qc[2].z*(K1).z + qc[2].w*(K1).w; \
        float sc3 = qa[3].x*(K0).x + qa[3].y*(K0).y + qa[3].z*(K0).z + qa[3].w*(K0).w \
                  + qc[3].x*(K1).x + qc[3].y*(K1).y + qc[3].z*(K1).z + qc[3].w*(K1).w; \
        sc0 = dpp_xor2_add(dpp_xor1_add(sc0));                                \
        sc1 = dpp_xor2_add(dpp_xor1_add(sc1));                                \
        sc2 = dpp_xor2_add(dpp_xor1_add(sc2));                                \
        sc3 = dpp_xor2_add(dpp_xor1_add(sc3));                                \
        float myv = (p == 0) ? sc0 : (p == 1) ? sc1 : (p == 2) ? sc2 : sc3;   \
        const int col = (w << 9) + ((T) << 4) + jg;                           \
        sbuf[p * SSTR + col] = myv;                                           \
        atomicAdd(&hist[p * 256 + (f2key(myv) >> 24)], 1u);                   \
    } while (0)

    // ---- Phase B: scores + top-byte histogram. Register ping-pong. ----
    float4 ka0 = *(const float4*)(KADDR(0));
    float4 ka1 = *(const float4*)(KADDR(0) + 4);
    float4 kb0 = *(const float4*)(KADDR(1));
    float4 kb1 = *(const float4*)(KADDR(1) + 4);
    #pragma unroll 1
    for (int t = 0; t < NT2; t += 2) {
        float4 c0 = ka0, c1 = ka1;
        if (t + 2 < NT2) { ka0 = *(const float4*)(KADDR(t + 2)); ka1 = *(const float4*)(KADDR(t + 2) + 4); }
        QK_TILE(c0, c1, t);
        float4 d0 = kb0, d1 = kb1;
        if (t + 3 < NT2) { kb0 = *(const float4*)(KADDR(t + 3)); kb1 = *(const float4*)(KADDR(t + 3) + 4); }
        QK_TILE(d0, d1, t + 1);
    }
    // preload V tiles 0,1 into registers; latency hides under radix/softmax
    float4 va0 = *(const float4*)(VADDR(0));
    float4 va1 = *(const float4*)(VADDR(0) + 4);
    float4 vb0 = *(const float4*)(VADDR(1));
    float4 vb1 = *(const float4*)(VADDR(1) + 4);
    RBAR();   // barrier 2: all scores + histogram atomics visible

    // ---- Phase C: exact 614th-largest per row. Wave w owns row w only. ----
    unsigned int* hrow = hist + w * 256;
    #pragma unroll 1
    for (int pass = 3; pass >= 0; --pass) {
        const int sh = pass * 8;
        const unsigned int pr = prefS[w];
        const int remv = remS[w];
        if (pass != 3) {
            const unsigned int hmsk = 0xFFFFFFFFu << (sh + 8);
            uint4 z4; z4.x = 0u; z4.y = 0u; z4.z = 0u; z4.w = 0u;
            *(uint4*)(hrow + l * 4) = z4;
            LGKM0();
            #pragma unroll 2
            for (int e = 0; e < 8; ++e) {
                float4 v = *(const float4*)&sbuf[w * SSTR + l * 4 + 256 * e];
                unsigned int k0 = f2key(v.x), k1 = f2key(v.y), k2 = f2key(v.z), k3 = f2key(v.w);
                if ((k0 & hmsk) == pr) atomicAdd(&hrow[(k0 >> sh) & 255u], 1u);
                if ((k1 & hmsk) == pr) atomicAdd(&hrow[(k1 >> sh) & 255u], 1u);
                if ((k2 & hmsk) == pr) atomicAdd(&hrow[(k2 >> sh) & 255u], 1u);
                if ((k3 & hmsk) == pr) atomicAdd(&hrow[(k3 >> sh) & 255u], 1u);
            }
            LGKM0();
        }
        uint4 c4 = *(const uint4*)(hrow + l * 4);
        unsigned int cnt[4] = { c4.x, c4.y, c4.z, c4.w };
        unsigned int part = cnt[0] + cnt[1] + cnt[2] + cnt[3];
        unsigned int suf = part;
        #pragma unroll
        for (int dlt = 1; dlt < 64; dlt <<= 1) {
            unsigned int v = __shfl_down(suf, dlt);
            if (l + dlt < 64) suf += v;
        }
        unsigned int run = suf - part;   // elems in bins owned by lanes > l
        #pragma unroll
        for (int i = 3; i >= 0; --i) {
            if ((int)run < remv && remv <= (int)(run + cnt[i])) {
                remS[w]  = remv - (int)run;
                prefS[w] = pr | ((unsigned int)(l * 4 + i) << sh);
            }
            run += cnt[i];
        }
        LGKM0();  // pref/rem visible wave-wide before next pass
    }

    // ---- Phase D: masked softmax on row w (float4, in LDS) ----
    {
        unsigned int key = prefS[w];
        unsigned int u = (key & 0x80000000u) ? (key & 0x7FFFFFFFu) : ~key;
        const float thr = __uint_as_float(u);
        float mx = 0.f;   // >=1434 masked zeros always present
        #pragma unroll 2
        for (int e = 0; e < 8; ++e) {
            float* sp = &sbuf[w * SSTR + l * 4 + 256 * e];
            float4 v = *(const float4*)sp;
            v.x = (v.x >= thr) ? v.x : 0.f;
            v.y = (v.y >= thr) ? v.y : 0.f;
            v.z = (v.z >= thr) ? v.z : 0.f;
            v.w = (v.w >= thr) ? v.w : 0.f;
            *(float4*)sp = v;
            mx = fmaxf(mx, fmaxf(fmaxf(v.x, v.y), fmaxf(v.z, v.w)));
        }
        #pragma unroll
        for (int d2 = 32; d2 >= 1; d2 >>= 1) mx = fmaxf(mx, __shfl_xor(mx, d2));
        float Z = 0.f;
        #pragma unroll 2
        for (int e = 0; e < 8; ++e) {
            float* sp = &sbuf[w * SSTR + l * 4 + 256 * e];
            float4 v = *(const float4*)sp;
            v.x = __expf(v.x - mx); v.y = __expf(v.y - mx);
            v.z = __expf(v.z - mx); v.w = __expf(v.w - mx);
            *(float4*)sp = v;
            Z += v.x + v.y + v.z + v.w;
        }
        #pragma unroll
        for (int d2 = 32; d2 >= 1; d2 >>= 1) Z += __shfl_xor(Z, d2);
        if (l == 0) zS[w] = Z;
    }
    RBAR();   // barrier 3: all rows' p-values + zS visible

    // ---- Phase E: PV. Register ping-pong over V, no barriers. ----
    float4 oa0, oa1, oa2, oa3, ob0, ob1, ob2, ob3;
    oa0.x=0;oa0.y=0;oa0.z=0;oa0.w=0; ob0=oa0; oa1=oa0; ob1=oa0;
    oa2=oa0; ob2=oa0; oa3=oa0; ob3=oa0;

#define PV_TILE(V0, V1, T) do {                                               \
        const int col = (w << 9) + ((T) << 4) + jg;                           \
        float p0 = sbuf[0 * SSTR + col];                                      \
        float p1 = sbuf[1 * SSTR + col];                                      \
        float p2 = sbuf[2 * SSTR + col];                                      \
        float p3 = sbuf[3 * SSTR + col];                                      \
        oa0.x=fmaf(p0,(V0).x,oa0.x); oa0.y=fmaf(p0,(V0).y,oa0.y); oa0.z=fmaf(p0,(V0).z,oa0.z); oa0.w=fmaf(p0,(V0).w,oa0.w); \
        ob0.x=fmaf(p0,(V1).x,ob0.x); ob0.y=fmaf(p0,(V1).y,ob0.y); ob0.z=fmaf(p0,(V1).z,ob0.z); ob0.w=fmaf(p0,(V1).w,ob0.w); \
        oa1.x=fmaf(p1,(V0).x,oa1.x); oa1.y=fmaf(p1,(V0).y,oa1.y); oa1.z=fmaf(p1,(V0).z,oa1.z); oa1.w=fmaf(p1,(V0).w,oa1.w); \
        ob1.x=fmaf(p1,(V1).x,ob1.x); ob1.y=fmaf(p1,(V1).y,ob1.y); ob1.z=fmaf(p1,(V1).z,ob1.z); ob1.w=fmaf(p1,(V1).w,ob1.w); \
        oa2.x=fmaf(p2,(V0).x,oa2.x); oa2.y=fmaf(p2,(V0).y,oa2.y); oa2.z=fmaf(p2,(V0).z,oa2.z); oa2.w=fmaf(p2,(V0).w,oa2.w); \
        ob2.x=fmaf(p2,(V1).x,ob2.x); ob2.y=fmaf(p2,(V1).y,ob2.y); ob2.z=fmaf(p2,(V1).z,ob2.z); ob2.w=fmaf(p2,(V1).w,ob2.w); \
        oa3.x=fmaf(p3,(V0).x,oa3.x); oa3.y=fmaf(p3,(V0).y,oa3.y); oa3.z=fmaf(p3,(V0).z,oa3.z); oa3.w=fmaf(p3,(V0).w,oa3.w); \
        ob3.x=fmaf(p3,(V1).x,ob3.x); ob3.y=fmaf(p3,(V1).y,ob3.y); ob3.z=fmaf(p3,(V1).z,ob3.z); ob3.w=fmaf(p3,(V1).w,ob3.w); \
    } while (0)

    #pragma unroll 1
    for (int t = 0; t < NT2; t += 2) {
        float4 c0 = va0, c1 = va1;
        if (t + 2 < NT2) { va0 = *(const float4*)(VADDR(t + 2)); va1 = *(const float4*)(VADDR(t + 2) + 4); }
        PV_TILE(c0, c1, t);
        float4 d0 = vb0, d1 = vb1;
        if (t + 3 < NT2) { vb0 = *(const float4*)(VADDR(t + 3)); vb1 = *(const float4*)(VADDR(t + 3) + 4); }
        PV_TILE(d0, d1, t + 1);
    }
    RBAR();   // barrier 4: all p-value reads done; sbuf reusable as partials

    // reduce over the 16 column-groups (lanes differing in bits 2..5)
    #pragma unroll
    for (int d2 = 4; d2 <= 32; d2 <<= 1) {
        oa0.x+=__shfl_xor(oa0.x,d2); oa0.y+=__shfl_xor(oa0.y,d2); oa0.z+=__shfl_xor(oa0.z,d2); oa0.w+=__shfl_xor(oa0.w,d2);
        ob0.x+=__shfl_xor(ob0.x,d2); ob0.y+=__shfl_xor(ob0.y,d2); ob0.z+=__shfl_xor(ob0.z,d2); ob0.w+=__shfl_xor(ob0.w,d2);
        oa1.x+=__shfl_xor(oa1.x,d2); oa1.y+=__shfl_xor(oa1.y,d2); oa1.z+=__shfl_xor(oa1.z,d2); oa1.w+=__shfl_xor(oa1.w,d2);
        ob1.x+=__shfl_xor(ob1.x,d2); ob1.y+=__shfl_xor(ob1.y,d2); ob1.z+=__shfl_xor(ob1.z,d2); ob1.w+=__shfl_xor(ob1.w,d2);
        oa2.x+=__shfl_xor(oa2.x,d2); oa2.y+=__shfl_xor(oa2.y,d2); oa2.z+=__shfl_xor(oa2.z,d2); oa2.w+=__shfl_xor(oa2.w,d2);
        ob2.x+=__shfl_xor(ob2.x,d2); ob2.y+=__shfl_xor(ob2.y,d2); ob2.z+=__shfl_xor(ob2.z,d2); ob2.w+=__shfl_xor(ob2.w,d2);
        oa3.x+=__shfl_xor(oa3.x,d2); oa3.y+=__shfl_xor(oa3.y,d2); oa3.z+=__shfl_xor(oa3.z,d2); oa3.w+=__shfl_xor(oa3.w,d2);
        ob3.x+=__shfl_xor(ob3.x,d2); ob3.y+=__shfl_xor(ob3.y,d2); ob3.z+=__shfl_xor(ob3.z,d2); ob3.w+=__shfl_xor(ob3.w,d2);
    }
    // lanes 0..3 of each wave hold dim-chunk l (=p) for all 4 rows
    if (l < 4) {
        float* part = &sbuf[0];   // [4 waves][4 rows][32 dims]
        *(float4*)&part[(w * 4 + 0) * 32 + l * 8]     = oa0;
        *(float4*)&part[(w * 4 + 0) * 32 + l * 8 + 4] = ob0;
        *(float4*)&part[(w * 4 + 1) * 32 + l * 8]     = oa1;
        *(float4*)&part[(w * 4 + 1) * 32 + l * 8 + 4] = ob1;
        *(float4*)&part[(w * 4 + 2) * 32 + l * 8]     = oa2;
        *(float4*)&part[(w * 4 + 2) * 32 + l * 8 + 4] = ob2;
        *(float4*)&part[(w * 4 + 3) * 32 + l * 8]     = oa3;
        *(float4*)&part[(w * 4 + 3) * 32 + l * 8 + 4] = ob3;
    }
    RBAR();   // barrier 5
    if (tid < 128) {
        const int r = tid >> 5, d = tid & 31;
        const float* part = &sbuf[0];
        float o = part[(0 * 4 + r) * 32 + d] + part[(1 * 4 + r) * 32 + d]
                + part[(2 * 4 + r) * 32 + d] + part[(3 * 4 + r) * 32 + d];
        o /= zS[r];
        aout[((size_t)b * NSEQ + n0 + r) * CDIM + h * 32 + d] = o;
    }
}

// -------------------------------------------------------------------------
extern "C" void kernel_launch(void* const* d_in, const int* in_sizes, int n_in,
                              void* d_out, int out_size, void* d_ws, size_t ws_size,
                              hipStream_t stream) {
    (void)in_sizes; (void)n_in; (void)out_size; (void)ws_size;
    const float* x      = (const float*)d_in[0];
    const float* w_qkv  = (const float*)d_in[1];
    const float* b_qkv  = (const float*)d_in[2];
    const float* w_proj = (const float*)d_in[3];
    const float* b_proj = (const float*)d_in[4];
    float* out = (float*)d_out;

    const int M = BDIM * NSEQ;  // 8192
    float* qkv_ws  = (float*)d_ws;                       // 25.2 MB
    float* attn_ws = qkv_ws + (size_t)M * 768;           // 8.4 MB

    // 1) QKV GEMM -> [B][N][3][H][D]
    dim3 g1(M / 64, 768 / 64);
    gemm_nt_bias<<<g1, 256, 0, stream>>>(x, w_qkv, b_qkv, qkv_ws, M, 768, 256);

    // 2) fused sparse attention -> [B][N][C]
    sparse_attn<<<BDIM * NHEADS * (NSEQ / QB), 256, 0, stream>>>(qkv_ws, attn_ws);

    // 3) projection GEMM -> d_out
    dim3 g2(M / 64, 256 / 64);
    gemm_nt_bias<<<g2, 256, 0, stream>>>(attn_ws, w_proj, b_proj, out, M, 256, 256);
}

// Round 9
// 653.801 us; speedup vs baseline: 2.4392x; 1.0205x over previous
//
#include <hip/hip_runtime.h>

// Problem constants (B=4, N=2048, C=256, H=8, D=32, keep = int(2048*0.3) = 614)
#define BDIM 4
#define NSEQ 2048
#define CDIM 256
#define NHEADS 8
#define QB 4                     // query rows per block (1 per wave)
#define NT2 32                   // per-wave tiles: 32 tiles x 16 rows = 512 cols
#define NKEEP 614                // int(2048 * (1.0 - 0.7))
#define SSTR 2056                // sbuf row stride (bank stagger)
#define ATTN_SCALE 0.17677669529663688f  // 32^-0.5

// -------------------------------------------------------------------------
// GEMM: C[M][Nt] = A[M][K] @ W[Nt][K]^T + bias[Nt]   (unchanged, validated)
// -------------------------------------------------------------------------
__global__ __launch_bounds__(256) void gemm_nt_bias(
    const float* __restrict__ A, const float* __restrict__ W,
    const float* __restrict__ bias, float* __restrict__ C,
    int M, int Nt, int K)
{
    __shared__ __align__(16) float As[32][68];
    __shared__ __align__(16) float Ws[32][68];
    const int tid = threadIdx.x;
    const int bm = blockIdx.x * 64;
    const int bn = blockIdx.y * 64;
    const int tm = tid >> 4;
    const int tn = tid & 15;
    const int lr = tid >> 2;
    const int lq = tid & 3;
    const float* Ap = A + (size_t)(bm + lr) * K + lq * 8;
    const float* Wp = W + (size_t)(bn + lr) * K + lq * 8;
    float acc[4][4] = {};

    for (int k0 = 0; k0 < K; k0 += 32) {
        float4 a0 = *(const float4*)(Ap + k0);
        float4 a1 = *(const float4*)(Ap + k0 + 4);
        float4 w0 = *(const float4*)(Wp + k0);
        float4 w1 = *(const float4*)(Wp + k0 + 4);
        __syncthreads();
        const int kq = lq * 8;
        As[kq+0][lr]=a0.x; As[kq+1][lr]=a0.y; As[kq+2][lr]=a0.z; As[kq+3][lr]=a0.w;
        As[kq+4][lr]=a1.x; As[kq+5][lr]=a1.y; As[kq+6][lr]=a1.z; As[kq+7][lr]=a1.w;
        Ws[kq+0][lr]=w0.x; Ws[kq+1][lr]=w0.y; Ws[kq+2][lr]=w0.z; Ws[kq+3][lr]=w0.w;
        Ws[kq+4][lr]=w1.x; Ws[kq+5][lr]=w1.y; Ws[kq+6][lr]=w1.z; Ws[kq+7][lr]=w1.w;
        __syncthreads();
        #pragma unroll
        for (int k = 0; k < 32; ++k) {
            float4 av = *(const float4*)&As[k][tm*4];
            float4 wv = *(const float4*)&Ws[k][tn*4];
            acc[0][0] += av.x*wv.x; acc[0][1] += av.x*wv.y; acc[0][2] += av.x*wv.z; acc[0][3] += av.x*wv.w;
            acc[1][0] += av.y*wv.x; acc[1][1] += av.y*wv.y; acc[1][2] += av.y*wv.z; acc[1][3] += av.y*wv.w;
            acc[2][0] += av.z*wv.x; acc[2][1] += av.z*wv.y; acc[2][2] += av.z*wv.z; acc[2][3] += av.z*wv.w;
            acc[3][0] += av.w*wv.x; acc[3][1] += av.w*wv.y; acc[3][2] += av.w*wv.z; acc[3][3] += av.w*wv.w;
        }
    }
    float4 bb = *(const float4*)(bias + bn + tn*4);
    #pragma unroll
    for (int i = 0; i < 4; ++i) {
        float4 o;
        o.x = acc[i][0] + bb.x;
        o.y = acc[i][1] + bb.y;
        o.z = acc[i][2] + bb.z;
        o.w = acc[i][3] + bb.w;
        *(float4*)(C + (size_t)(bm + tm*4 + i) * Nt + bn + tn*4) = o;
    }
}

// -------------------------------------------------------------------------
// Fused sparse attention — per-wave streaming, K/V direct global->register,
// 4-deep register pipeline (covers ~400cyc L2 latency). Scores in LDS.
// 5 block barriers total.
// -------------------------------------------------------------------------
__device__ __forceinline__ unsigned int f2key(float f) {
    unsigned int u = __float_as_uint(f);
    return (u & 0x80000000u) ? ~u : (u | 0x80000000u);  // monotone order-preserving
}

// cross-lane add within quad: xor1 = quad_perm(1,0,3,2)=0xB1, xor2 = (2,3,0,1)=0x4E
__device__ __forceinline__ float dpp_xor1_add(float x) {
    int s = __builtin_amdgcn_mov_dpp(__float_as_int(x), 0xB1, 0xF, 0xF, true);
    return x + __int_as_float(s);
}
__device__ __forceinline__ float dpp_xor2_add(float x) {
    int s = __builtin_amdgcn_mov_dpp(__float_as_int(x), 0x4E, 0xF, 0xF, true);
    return x + __int_as_float(s);
}

// raw barrier: drain LDS ops, do NOT drain vmcnt (keeps prefetch in flight)
#define RBAR() do { asm volatile("s_waitcnt lgkmcnt(0)" ::: "memory"); \
                    __builtin_amdgcn_s_barrier();                      \
                    asm volatile("" ::: "memory"); } while (0)
#define LGKM0() asm volatile("s_waitcnt lgkmcnt(0)" ::: "memory")

__global__ __launch_bounds__(256, 4) void sparse_attn(
    const float* __restrict__ qkv, float* __restrict__ aout)
{
    __shared__ __align__(16) float  sbuf[QB * SSTR];        // 32.1 KB scores / p-values
    __shared__ __align__(16) unsigned int hist[QB * 256];   // 4 KB
    __shared__ unsigned int prefS[QB];
    __shared__ int   remS[QB];
    __shared__ float zS[QB];

    const int tid = threadIdx.x;
    const int w   = tid >> 6;       // wave id = row id (0..3) = column-range owner
    const int l   = tid & 63;
    const int p   = l & 3;          // dim-chunk pair (8 floats at 8p)
    const int jg  = l >> 2;         // 0..15 = row within a 16-row tile

    const int blk = blockIdx.x;
    const int nqb = NSEQ / QB;      // 512
    const int bh  = blk / nqb;
    const int qblk = blk % nqb;
    const int b = bh / NHEADS, h = bh % NHEADS;
    const int n0 = qblk * QB;

    const float* base = qkv + (size_t)b * NSEQ * 768;
    // this thread's K/V column pointers: column = 512w + t*16 + jg, dims [8p, 8p+8)
    const float* kptr = base + 256 + h * 32 + p * 8 + (size_t)((w << 9) + jg) * 768;
    const float* vptr = base + 512 + h * 32 + p * 8 + (size_t)((w << 9) + jg) * 768;
#define KADDR(t) (kptr + (size_t)(t) * (16 * 768))
#define VADDR(t) (vptr + (size_t)(t) * (16 * 768))

    // ---- Q rows 0..3, this lane's 8-dim chunk, pre-scaled, in registers ----
    float4 qa[QB], qc[QB];
    {
        const float* gq = base + (size_t)n0 * 768 + h * 32 + p * 8;
        #pragma unroll
        for (int r = 0; r < QB; ++r) {
            float4 x0 = *(const float4*)(gq + (size_t)r * 768);
            float4 x1 = *(const float4*)(gq + (size_t)r * 768 + 4);
            qa[r].x = x0.x * ATTN_SCALE; qa[r].y = x0.y * ATTN_SCALE;
            qa[r].z = x0.z * ATTN_SCALE; qa[r].w = x0.w * ATTN_SCALE;
            qc[r].x = x1.x * ATTN_SCALE; qc[r].y = x1.y * ATTN_SCALE;
            qc[r].z = x1.z * ATTN_SCALE; qc[r].w = x1.w * ATTN_SCALE;
        }
    }
    // zero pass-3 histogram (filled inline during phase B by all waves)
    {
        uint4 z4; z4.x = 0u; z4.y = 0u; z4.z = 0u; z4.w = 0u;
        *(uint4*)(hist + tid * 4) = z4;
    }
    if (tid < QB) { prefS[tid] = 0u; remS[tid] = NKEEP; }
    RBAR();   // barrier 1: hist/prefS initialized before any atomic

    // per-tile score computation: K chunk regs -> 4 row scores -> sbuf + hist
#define QK_TILE(K0, K1, T) do {                                               \
        float sc0 = qa[0].x*(K0).x + qa[0].y*(K0).y + qa[0].z*(K0).z + qa[0].w*(K0).w \
                  + qc[0].x*(K1).x + qc[0].y*(K1).y + qc[0].z*(K1).z + qc[0].w*(K1).w; \
        float sc1 = qa[1].x*(K0).x + qa[1].y*(K0).y + qa[1].z*(K0).z + qa[1].w*(K0).w \
                  + qc[1].x*(K1).x + qc[1].y*(K1).y + qc[1].z*(K1).z + qc[1].w*(K1).w; \
        float sc2 = qa[2].x*(K0).x + qa[2].y*(K0).y + qa[2].z*(K0).z + qa[2].w*(K0).w \
                  + qc[2].x*(K1).x + qc[2].y*(K1).y + qc[2].z*(K1).z + qc[2].w*(K1).w; \
        float sc3 = qa[3].x*(K0).x + qa[3].y*(K0).y + qa[3].z*(K0).z + qa[3].w*(K0).w \
                  + qc[3].x*(K1).x + qc[3].y*(K1).y + qc[3].z*(K1).z + qc[3].w*(K1).w; \
        sc0 = dpp_xor2_add(dpp_xor1_add(sc0));                                \
        sc1 = dpp_xor2_add(dpp_xor1_add(sc1));                                \
        sc2 = dpp_xor2_add(dpp_xor1_add(sc2));                                \
        sc3 = dpp_xor2_add(dpp_xor1_add(sc3));                                \
        float myv = (p == 0) ? sc0 : (p == 1) ? sc1 : (p == 2) ? sc2 : sc3;   \
        const int col = (w << 9) + ((T) << 4) + jg;                           \
        sbuf[p * SSTR + col] = myv;                                           \
        atomicAdd(&hist[p * 256 + (f2key(myv) >> 24)], 1u);                   \
    } while (0)

    // ---- Phase B: scores + top-byte histogram. 4-deep register pipeline. ----
    float4 ka0 = *(const float4*)(KADDR(0)), ka1 = *(const float4*)(KADDR(0) + 4);
    float4 kb0 = *(const float4*)(KADDR(1)), kb1 = *(const float4*)(KADDR(1) + 4);
    float4 kc0 = *(const float4*)(KADDR(2)), kc1 = *(const float4*)(KADDR(2) + 4);
    float4 kd0 = *(const float4*)(KADDR(3)), kd1 = *(const float4*)(KADDR(3) + 4);
    #pragma unroll 1
    for (int t = 0; t < NT2; t += 4) {
        float4 c0, c1;
        c0 = ka0; c1 = ka1;
        if (t + 4 < NT2) { ka0 = *(const float4*)(KADDR(t + 4)); ka1 = *(const float4*)(KADDR(t + 4) + 4); }
        QK_TILE(c0, c1, t);
        c0 = kb0; c1 = kb1;
        if (t + 5 < NT2) { kb0 = *(const float4*)(KADDR(t + 5)); kb1 = *(const float4*)(KADDR(t + 5) + 4); }
        QK_TILE(c0, c1, t + 1);
        c0 = kc0; c1 = kc1;
        if (t + 6 < NT2) { kc0 = *(const float4*)(KADDR(t + 6)); kc1 = *(const float4*)(KADDR(t + 6) + 4); }
        QK_TILE(c0, c1, t + 2);
        c0 = kd0; c1 = kd1;
        if (t + 7 < NT2) { kd0 = *(const float4*)(KADDR(t + 7)); kd1 = *(const float4*)(KADDR(t + 7) + 4); }
        QK_TILE(c0, c1, t + 3);
    }
    // preload V tiles 0..3 into registers; latency hides under radix/softmax
    float4 va0 = *(const float4*)(VADDR(0)), va1 = *(const float4*)(VADDR(0) + 4);
    float4 vb0 = *(const float4*)(VADDR(1)), vb1 = *(const float4*)(VADDR(1) + 4);
    float4 vc0 = *(const float4*)(VADDR(2)), vc1 = *(const float4*)(VADDR(2) + 4);
    float4 vd0 = *(const float4*)(VADDR(3)), vd1 = *(const float4*)(VADDR(3) + 4);
    RBAR();   // barrier 2: all scores + histogram atomics visible

    // ---- Phase C: exact 614th-largest per row. Wave w owns row w only. ----
    unsigned int* hrow = hist + w * 256;
    #pragma unroll 1
    for (int pass = 3; pass >= 0; --pass) {
        const int sh = pass * 8;
        const unsigned int pr = prefS[w];
        const int remv = remS[w];
        if (pass != 3) {
            const unsigned int hmsk = 0xFFFFFFFFu << (sh + 8);
            uint4 z4; z4.x = 0u; z4.y = 0u; z4.z = 0u; z4.w = 0u;
            *(uint4*)(hrow + l * 4) = z4;
            LGKM0();
            #pragma unroll 2
            for (int e = 0; e < 8; ++e) {
                float4 v = *(const float4*)&sbuf[w * SSTR + l * 4 + 256 * e];
                unsigned int k0 = f2key(v.x), k1 = f2key(v.y), k2 = f2key(v.z), k3 = f2key(v.w);
                if ((k0 & hmsk) == pr) atomicAdd(&hrow[(k0 >> sh) & 255u], 1u);
                if ((k1 & hmsk) == pr) atomicAdd(&hrow[(k1 >> sh) & 255u], 1u);
                if ((k2 & hmsk) == pr) atomicAdd(&hrow[(k2 >> sh) & 255u], 1u);
                if ((k3 & hmsk) == pr) atomicAdd(&hrow[(k3 >> sh) & 255u], 1u);
            }
            LGKM0();
        }
        uint4 c4 = *(const uint4*)(hrow + l * 4);
        unsigned int cnt[4] = { c4.x, c4.y, c4.z, c4.w };
        unsigned int part = cnt[0] + cnt[1] + cnt[2] + cnt[3];
        unsigned int suf = part;
        #pragma unroll
        for (int dlt = 1; dlt < 64; dlt <<= 1) {
            unsigned int v = __shfl_down(suf, dlt);
            if (l + dlt < 64) suf += v;
        }
        unsigned int run = suf - part;   // elems in bins owned by lanes > l
        #pragma unroll
        for (int i = 3; i >= 0; --i) {
            if ((int)run < remv && remv <= (int)(run + cnt[i])) {
                remS[w]  = remv - (int)run;
                prefS[w] = pr | ((unsigned int)(l * 4 + i) << sh);
            }
            run += cnt[i];
        }
        LGKM0();  // pref/rem visible wave-wide before next pass
    }

    // ---- Phase D: masked softmax on row w (float4, in LDS) ----
    {
        unsigned int key = prefS[w];
        unsigned int u = (key & 0x80000000u) ? (key & 0x7FFFFFFFu) : ~key;
        const float thr = __uint_as_float(u);
        float mx = 0.f;   // >=1434 masked zeros always present
        #pragma unroll 2
        for (int e = 0; e < 8; ++e) {
            float* sp = &sbuf[w * SSTR + l * 4 + 256 * e];
            float4 v = *(const float4*)sp;
            v.x = (v.x >= thr) ? v.x : 0.f;
            v.y = (v.y >= thr) ? v.y : 0.f;
            v.z = (v.z >= thr) ? v.z : 0.f;
            v.w = (v.w >= thr) ? v.w : 0.f;
            *(float4*)sp = v;
            mx = fmaxf(mx, fmaxf(fmaxf(v.x, v.y), fmaxf(v.z, v.w)));
        }
        #pragma unroll
        for (int d2 = 32; d2 >= 1; d2 >>= 1) mx = fmaxf(mx, __shfl_xor(mx, d2));
        float Z = 0.f;
        const float cm = __expf(0.f - mx);   // masked-entry value
        if (thr > 0.f) {
            // kept values >= thr > 0, masked == 0 exactly -> v>0 discriminates
            #pragma unroll 2
            for (int e = 0; e < 8; ++e) {
                float* sp = &sbuf[w * SSTR + l * 4 + 256 * e];
                float4 v = *(const float4*)sp;
                v.x = (v.x > 0.f) ? __expf(v.x - mx) : cm;
                v.y = (v.y > 0.f) ? __expf(v.y - mx) : cm;
                v.z = (v.z > 0.f) ? __expf(v.z - mx) : cm;
                v.w = (v.w > 0.f) ? __expf(v.w - mx) : cm;
                *(float4*)sp = v;
                Z += v.x + v.y + v.z + v.w;
            }
        } else {
            #pragma unroll 2
            for (int e = 0; e < 8; ++e) {
                float* sp = &sbuf[w * SSTR + l * 4 + 256 * e];
                float4 v = *(const float4*)sp;
                v.x = __expf(v.x - mx); v.y = __expf(v.y - mx);
                v.z = __expf(v.z - mx); v.w = __expf(v.w - mx);
                *(float4*)sp = v;
                Z += v.x + v.y + v.z + v.w;
            }
        }
        #pragma unroll
        for (int d2 = 32; d2 >= 1; d2 >>= 1) Z += __shfl_xor(Z, d2);
        if (l == 0) zS[w] = Z;
    }
    RBAR();   // barrier 3: all rows' p-values + zS visible

    // ---- Phase E: PV. 4-deep register pipeline over V, no barriers. ----
    float4 oa0, oa1, oa2, oa3, ob0, ob1, ob2, ob3;
    oa0.x=0;oa0.y=0;oa0.z=0;oa0.w=0; ob0=oa0; oa1=oa0; ob1=oa0;
    oa2=oa0; ob2=oa0; oa3=oa0; ob3=oa0;

#define PV_TILE(V0, V1, T) do {                                               \
        const int col = (w << 9) + ((T) << 4) + jg;                           \
        float p0 = sbuf[0 * SSTR + col];                                      \
        float p1 = sbuf[1 * SSTR + col];                                      \
        float p2 = sbuf[2 * SSTR + col];                                      \
        float p3 = sbuf[3 * SSTR + col];                                      \
        oa0.x=fmaf(p0,(V0).x,oa0.x); oa0.y=fmaf(p0,(V0).y,oa0.y); oa0.z=fmaf(p0,(V0).z,oa0.z); oa0.w=fmaf(p0,(V0).w,oa0.w); \
        ob0.x=fmaf(p0,(V1).x,ob0.x); ob0.y=fmaf(p0,(V1).y,ob0.y); ob0.z=fmaf(p0,(V1).z,ob0.z); ob0.w=fmaf(p0,(V1).w,ob0.w); \
        oa1.x=fmaf(p1,(V0).x,oa1.x); oa1.y=fmaf(p1,(V0).y,oa1.y); oa1.z=fmaf(p1,(V0).z,oa1.z); oa1.w=fmaf(p1,(V0).w,oa1.w); \
        ob1.x=fmaf(p1,(V1).x,ob1.x); ob1.y=fmaf(p1,(V1).y,ob1.y); ob1.z=fmaf(p1,(V1).z,ob1.z); ob1.w=fmaf(p1,(V1).w,ob1.w); \
        oa2.x=fmaf(p2,(V0).x,oa2.x); oa2.y=fmaf(p2,(V0).y,oa2.y); oa2.z=fmaf(p2,(V0).z,oa2.z); oa2.w=fmaf(p2,(V0).w,oa2.w); \
        ob2.x=fmaf(p2,(V1).x,ob2.x); ob2.y=fmaf(p2,(V1).y,ob2.y); ob2.z=fmaf(p2,(V1).z,ob2.z); ob2.w=fmaf(p2,(V1).w,ob2.w); \
        oa3.x=fmaf(p3,(V0).x,oa3.x); oa3.y=fmaf(p3,(V0).y,oa3.y); oa3.z=fmaf(p3,(V0).z,oa3.z); oa3.w=fmaf(p3,(V0).w,oa3.w); \
        ob3.x=fmaf(p3,(V1).x,ob3.x); ob3.y=fmaf(p3,(V1).y,ob3.y); ob3.z=fmaf(p3,(V1).z,ob3.z); ob3.w=fmaf(p3,(V1).w,ob3.w); \
    } while (0)

    #pragma unroll 1
    for (int t = 0; t < NT2; t += 4) {
        float4 c0, c1;
        c0 = va0; c1 = va1;
        if (t + 4 < NT2) { va0 = *(const float4*)(VADDR(t + 4)); va1 = *(const float4*)(VADDR(t + 4) + 4); }
        PV_TILE(c0, c1, t);
        c0 = vb0; c1 = vb1;
        if (t + 5 < NT2) { vb0 = *(const float4*)(VADDR(t + 5)); vb1 = *(const float4*)(VADDR(t + 5) + 4); }
        PV_TILE(c0, c1, t + 1);
        c0 = vc0; c1 = vc1;
        if (t + 6 < NT2) { vc0 = *(const float4*)(VADDR(t + 6)); vc1 = *(const float4*)(VADDR(t + 6) + 4); }
        PV_TILE(c0, c1, t + 2);
        c0 = vd0; c1 = vd1;
        if (t + 7 < NT2) { vd0 = *(const float4*)(VADDR(t + 7)); vd1 = *(const float4*)(VADDR(t + 7) + 4); }
        PV_TILE(c0, c1, t + 3);
    }
    RBAR();   // barrier 4: all p-value reads done; sbuf reusable as partials

    // reduce over the 16 column-groups (lanes differing in bits 2..5)
    #pragma unroll
    for (int d2 = 4; d2 <= 32; d2 <<= 1) {
        oa0.x+=__shfl_xor(oa0.x,d2); oa0.y+=__shfl_xor(oa0.y,d2); oa0.z+=__shfl_xor(oa0.z,d2); oa0.w+=__shfl_xor(oa0.w,d2);
        ob0.x+=__shfl_xor(ob0.x,d2); ob0.y+=__shfl_xor(ob0.y,d2); ob0.z+=__shfl_xor(ob0.z,d2); ob0.w+=__shfl_xor(ob0.w,d2);
        oa1.x+=__shfl_xor(oa1.x,d2); oa1.y+=__shfl_xor(oa1.y,d2); oa1.z+=__shfl_xor(oa1.z,d2); oa1.w+=__shfl_xor(oa1.w,d2);
        ob1.x+=__shfl_xor(ob1.x,d2); ob1.y+=__shfl_xor(ob1.y,d2); ob1.z+=__shfl_xor(ob1.z,d2); ob1.w+=__shfl_xor(ob1.w,d2);
        oa2.x+=__shfl_xor(oa2.x,d2); oa2.y+=__shfl_xor(oa2.y,d2); oa2.z+=__shfl_xor(oa2.z,d2); oa2.w+=__shfl_xor(oa2.w,d2);
        ob2.x+=__shfl_xor(ob2.x,d2); ob2.y+=__shfl_xor(ob2.y,d2); ob2.z+=__shfl_xor(ob2.z,d2); ob2.w+=__shfl_xor(ob2.w,d2);
        oa3.x+=__shfl_xor(oa3.x,d2); oa3.y+=__shfl_xor(oa3.y,d2); oa3.z+=__shfl_xor(oa3.z,d2); oa3.w+=__shfl_xor(oa3.w,d2);
        ob3.x+=__shfl_xor(ob3.x,d2); ob3.y+=__shfl_xor(ob3.y,d2); ob3.z+=__shfl_xor(ob3.z,d2); ob3.w+=__shfl_xor(ob3.w,d2);
    }
    // lanes 0..3 of each wave hold dim-chunk l (=p) for all 4 rows
    if (l < 4) {
        float* part = &sbuf[0];   // [4 waves][4 rows][32 dims]
        *(float4*)&part[(w * 4 + 0) * 32 + l * 8]     = oa0;
        *(float4*)&part[(w * 4 + 0) * 32 + l * 8 + 4] = ob0;
        *(float4*)&part[(w * 4 + 1) * 32 + l * 8]     = oa1;
        *(float4*)&part[(w * 4 + 1) * 32 + l * 8 + 4] = ob1;
        *(float4*)&part[(w * 4 + 2) * 32 + l * 8]     = oa2;
        *(float4*)&part[(w * 4 + 2) * 32 + l * 8 + 4] = ob2;
        *(float4*)&part[(w * 4 + 3) * 32 + l * 8]     = oa3;
        *(float4*)&part[(w * 4 + 3) * 32 + l * 8 + 4] = ob3;
    }
    RBAR();   // barrier 5
    if (tid < 128) {
        const int r = tid >> 5, d = tid & 31;
        const float* part = &sbuf[0];
        float o = part[(0 * 4 + r) * 32 + d] + part[(1 * 4 + r) * 32 + d]
                + part[(2 * 4 + r) * 32 + d] + part[(3 * 4 + r) * 32 + d];
        o /= zS[r];
        aout[((size_t)b * NSEQ + n0 + r) * CDIM + h * 32 + d] = o;
    }
}

// -------------------------------------------------------------------------
extern "C" void kernel_launch(void* const* d_in, const int* in_sizes, int n_in,
                              void* d_out, int out_size, void* d_ws, size_t ws_size,
                              hipStream_t stream) {
    (void)in_sizes; (void)n_in; (void)out_size; (void)ws_size;
    const float* x      = (const float*)d_in[0];
    const float* w_qkv  = (const float*)d_in[1];
    const float* b_qkv  = (const float*)d_in[2];
    const float* w_proj = (const float*)d_in[3];
    const float* b_proj = (const float*)d_in[4];
    float* out = (float*)d_out;

    const int M = BDIM * NSEQ;  // 8192
    float* qkv_ws  = (float*)d_ws;                       // 25.2 MB
    float* attn_ws = qkv_ws + (size_t)M * 768;           // 8.4 MB

    // 1) QKV GEMM -> [B][N][3][H][D]
    dim3 g1(M / 64, 768 / 64);
    gemm_nt_bias<<<g1, 256, 0, stream>>>(x, w_qkv, b_qkv, qkv_ws, M, 768, 256);

    // 2) fused sparse attention -> [B][N][C]
    sparse_attn<<<BDIM * NHEADS * (NSEQ / QB), 256, 0, stream>>>(qkv_ws, attn_ws);

    // 3) projection GEMM -> d_out
    dim3 g2(M / 64, 256 / 64);
    gemm_nt_bias<<<g2, 256, 0, stream>>>(attn_ws, w_proj, b_proj, out, M, 256, 256);
}